// Round 1
// baseline (134.165 us; speedup 1.0000x reference)
//
#include <hip/hip_runtime.h>

// Locally-connected 2D: out[b,o,y,x] = sum_{c,kh,kw} x[b,c,y+kh,x+kw] * W[y,x,o,c*25+kh*5+kw] + bias[y,x,o]
// x: [128,3,64,64] f32, W: [60,60,32,75] f32, bias: [60,60,32] f32, out: [128,32,60,60] f32.
//
// Strategy: per-position GEMM M=128,N=32,K=75 via bf16 MFMA (no fp32 MFMA on CDNA4).
// One block handles one (y, x-pair). K re-indexed to k' = c*30+kh*6+w so both x
// positions share the A (patch) matrix; W staged as 2 shift-padded copies in LDS.
// K' = 90 padded to 96 -> 3 MFMA K-steps of 32.

#define RY 60
#define RX 60
#define OC 32
#define BATCH 128
#define CIN 3
#define HW 64
#define KHH 5
#define KWW 5
#define KLD 104   // bf16 row stride: 208 B = 13*16 B (odd multiple of 16B -> conflict-light)
#define XT 2      // x positions per block

typedef __attribute__((ext_vector_type(8))) short short8;
typedef __attribute__((ext_vector_type(4))) float f32x4;

__device__ __forceinline__ ushort bf16r(float f) {
    union { float f; unsigned u; } v; v.f = f;
    return (ushort)((v.u + 0x7FFFu + ((v.u >> 16) & 1u)) >> 16);  // RNE
}

__global__ __launch_bounds__(256, 4) void lc2d_kernel(
    const float* __restrict__ x, const float* __restrict__ w,
    const float* __restrict__ bias, float* __restrict__ out)
{
    __shared__ ushort pa[BATCH][KLD];    // patches, bf16: 26624 B
    __shared__ ushort wt[XT][OC][KLD];   // shifted W copies, bf16: 13312 B
    __shared__ float  bl[XT][OC];        // bias: 256 B

    const int tid = threadIdx.x;
    const int x0  = blockIdx.x * XT;   // 0,2,...,58
    const int y   = blockIdx.y;        // 0..59

    // ---- zero wt (zeros implement the shift-padding) + pa tail (k' in [90,96)) ----
    {
        unsigned* wz = (unsigned*)&wt[0][0][0];
        const int nw = XT * OC * KLD / 2;  // 3328 uints
        for (int i = tid; i < nw; i += 256) wz[i] = 0u;
        for (int i = tid; i < BATCH * 3; i += 256) {
            int b = i / 3, j = i % 3;
            ((unsigned*)&pa[b][90])[j] = 0u;   // byte offset 180 within row: 4B aligned
        }
    }
    __syncthreads();

    // ---- stage patches: 1920 rows of 6 floats -> bf16 ----
    for (int r = tid; r < BATCH * CIN * KHH; r += 256) {
        const int b  = r / (CIN * KHH);
        const int cm = r % (CIN * KHH);
        const int c  = cm / KHH;
        const int kh = cm % KHH;
        const float* src = x + (size_t)((b * CIN + c) * HW + (y + kh)) * HW + x0;
        float2 v0 = *(const float2*)(src);
        float2 v1 = *(const float2*)(src + 2);
        float2 v2 = *(const float2*)(src + 4);
        unsigned* dst = (unsigned*)&pa[b][c * 30 + kh * 6];  // byte off 60c+12kh: 4B aligned
        dst[0] = (unsigned)bf16r(v0.x) | ((unsigned)bf16r(v0.y) << 16);
        dst[1] = (unsigned)bf16r(v1.x) | ((unsigned)bf16r(v1.y) << 16);
        dst[2] = (unsigned)bf16r(v2.x) | ((unsigned)bf16r(v2.y) << 16);
    }

    // ---- stage W: 2 shift-padded bf16 copies (each position's W read once, coalesced) ----
    for (int xi = 0; xi < XT; ++xi) {
        const float* wsrc = w + (size_t)(y * RX + x0 + xi) * (OC * 75);
        for (int i = tid; i < OC * 75; i += 256) {
            const float val = wsrc[i];
            const int o  = i / 75;
            const int km = i % 75;
            const int c  = km / 25;
            const int rm = km % 25;
            const int kh = rm / 5;
            const int kw = rm % 5;
            wt[xi][o][c * 30 + kh * 6 + kw + xi] = bf16r(val);
        }
    }
    if (tid < XT * OC) {
        const int xi = tid >> 5, o = tid & 31;
        bl[xi][o] = bias[(size_t)(y * RX + x0 + xi) * OC + o];
    }
    __syncthreads();

    // ---- MFMA compute: wave wid owns rows [wid*32, wid*32+32) x both N-tiles x both xi ----
    const int wid  = tid >> 6;
    const int lane = tid & 63;
    const int lrow = lane & 15;
    const int lgrp = lane >> 4;        // 0..3
    const int mbase = wid * 32;

    f32x4 acc[2][2][2];                // [mt][nt][xi]
    #pragma unroll
    for (int mt = 0; mt < 2; ++mt)
        #pragma unroll
        for (int nt = 0; nt < 2; ++nt)
            #pragma unroll
            for (int xi = 0; xi < 2; ++xi)
                acc[mt][nt][xi] = (f32x4){0.f, 0.f, 0.f, 0.f};

    #pragma unroll
    for (int ks = 0; ks < 3; ++ks) {
        const int koff = ks * 32 + lgrp * 8;   // 16B-aligned byte offset *2
        const short8 af0 = *(const short8*)&pa[mbase + lrow][koff];
        const short8 af1 = *(const short8*)&pa[mbase + 16 + lrow][koff];
        const short8 b00 = *(const short8*)&wt[0][lrow][koff];        // nt=0, xi=0
        const short8 b10 = *(const short8*)&wt[1][lrow][koff];        // nt=0, xi=1
        const short8 b01 = *(const short8*)&wt[0][16 + lrow][koff];   // nt=1, xi=0
        const short8 b11 = *(const short8*)&wt[1][16 + lrow][koff];   // nt=1, xi=1
        acc[0][0][0] = __builtin_amdgcn_mfma_f32_16x16x32_bf16(af0, b00, acc[0][0][0], 0, 0, 0);
        acc[0][0][1] = __builtin_amdgcn_mfma_f32_16x16x32_bf16(af0, b10, acc[0][0][1], 0, 0, 0);
        acc[0][1][0] = __builtin_amdgcn_mfma_f32_16x16x32_bf16(af0, b01, acc[0][1][0], 0, 0, 0);
        acc[0][1][1] = __builtin_amdgcn_mfma_f32_16x16x32_bf16(af0, b11, acc[0][1][1], 0, 0, 0);
        acc[1][0][0] = __builtin_amdgcn_mfma_f32_16x16x32_bf16(af1, b00, acc[1][0][0], 0, 0, 0);
        acc[1][0][1] = __builtin_amdgcn_mfma_f32_16x16x32_bf16(af1, b10, acc[1][0][1], 0, 0, 0);
        acc[1][1][0] = __builtin_amdgcn_mfma_f32_16x16x32_bf16(af1, b01, acc[1][1][0], 0, 0, 0);
        acc[1][1][1] = __builtin_amdgcn_mfma_f32_16x16x32_bf16(af1, b11, acc[1][1][1], 0, 0, 0);
    }

    // ---- epilogue: bias add + float2 stores (two x positions contiguous in output) ----
    const int pos = y * RX + x0;
    #pragma unroll
    for (int mt = 0; mt < 2; ++mt) {
        #pragma unroll
        for (int nt = 0; nt < 2; ++nt) {
            const int o = nt * 16 + lrow;
            const float bv0 = bl[0][o];
            const float bv1 = bl[1][o];
            const int brow = mbase + mt * 16 + lgrp * 4;
            #pragma unroll
            for (int r = 0; r < 4; ++r) {
                float2 v;
                v.x = acc[mt][nt][0][r] + bv0;
                v.y = acc[mt][nt][1][r] + bv1;
                *(float2*)(out + (size_t)((brow + r) * OC + o) * (RY * RX) + pos) = v;
            }
        }
    }
}

extern "C" void kernel_launch(void* const* d_in, const int* in_sizes, int n_in,
                              void* d_out, int out_size, void* d_ws, size_t ws_size,
                              hipStream_t stream) {
    const float* x    = (const float*)d_in[0];
    const float* w    = (const float*)d_in[1];
    const float* bias = (const float*)d_in[2];
    float* out        = (float*)d_out;
    dim3 grid(RX / XT, RY);  // 30 x 60 = 1800 blocks
    lc2d_kernel<<<grid, 256, 0, stream>>>(x, w, bias, out);
}

// Round 2
// 55.274 us; speedup vs baseline: 2.4272x; 2.4272x over previous
//
#include <hip/hip_runtime.h>

// Locally-connected 2D: out[b,o,y,x] = sum_{c,kh,kw} x[b,c,y+kh,x+kw] * W[y,x,o,c*25+kh*5+kw] + bias[y,x,o]
// x: [128,3,64,64] f32, W: [60,60,32,75] f32, bias: [60,60,32] f32, out: [128,32,60,60] f32.
//
// Phase 1: per-position GEMM M=128,N=32,K=75 via bf16 MFMA. One block = one (y, x-pair).
// K re-indexed to k' = c*30+kh*6+w so both x positions share the A (patch) matrix;
// W staged as 2 shift-padded copies in LDS. K' = 90 padded to 96 -> 3 MFMA K-steps.
// Epilogue writes tmp[pos][b*32+o][xi] -> full-cache-line wave stores (fixes the 4.4x
// WRITE_SIZE amplification of the direct [b][o][y][x] scatter).
// Phase 2: LDS tile transpose tmp -> out, coalesced both sides.
// Fallback to direct scatter epilogue if ws_size is too small for tmp (59 MB).

#define RY 60
#define RX 60
#define OC 32
#define BATCH 128
#define CIN 3
#define HW 64
#define KHH 5
#define KLD 104   // bf16 row stride: 208 B = 13*16 B (odd multiple of 16B -> conflict-light)
#define XT 2      // x positions per block

typedef __attribute__((ext_vector_type(8))) short short8;
typedef __attribute__((ext_vector_type(4))) float f32x4;

__device__ __forceinline__ ushort bf16r(float f) {
    union { float f; unsigned u; } v; v.f = f;
    return (ushort)((v.u + 0x7FFFu + ((v.u >> 16) & 1u)) >> 16);  // RNE
}

template<bool COAL>
__global__ __launch_bounds__(256, 4) void lc2d_k1(
    const float* __restrict__ x, const float* __restrict__ w,
    const float* __restrict__ bias, float* __restrict__ outp,
    float* __restrict__ tmp)
{
    __shared__ ushort pa[BATCH][KLD];    // patches, bf16: 26624 B
    __shared__ ushort wt[XT][OC][KLD];   // shifted W copies, bf16: 13312 B
    __shared__ float  bl[XT][OC];        // bias

    const int tid = threadIdx.x;
    // XCD-chunked block mapping: 1800 blocks, 225 per XCD, xp-major within chunk
    // -> x-adjacent blocks share an XCD L2 (write merging + W/x locality).
    const int id  = blockIdx.x;
    const int lin = (id & 7) * 225 + (id >> 3);
    const int xp  = lin % 30;
    const int y   = lin / 30;
    const int x0  = xp * XT;

    // ---- zero wt (zeros implement the shift-padding) + pa tail (k' in [90,96)) ----
    {
        unsigned* wz = (unsigned*)&wt[0][0][0];
        const int nw = XT * OC * KLD / 2;
        for (int i = tid; i < nw; i += 256) wz[i] = 0u;
        for (int i = tid; i < BATCH * 3; i += 256) {
            int b = i / 3, j = i % 3;
            ((unsigned*)&pa[b][90])[j] = 0u;
        }
    }
    __syncthreads();

    // ---- stage W first (cold HBM, long latency): float4 loads, bf16 scatter ----
    for (int xi = 0; xi < XT; ++xi) {
        const float4* ws4 = (const float4*)(w + (size_t)(y * RX + x0 + xi) * (OC * 75));
        for (int i = tid; i < OC * 75 / 4; i += 256) {
            const float4 v = ws4[i];
            const int base = i * 4;
            #pragma unroll
            for (int j = 0; j < 4; ++j) {
                const int k  = base + j;
                const int o  = k / 75;
                const int km = k % 75;
                const int c  = km / 25;
                const int rm = km % 25;
                const int kh = rm / 5;
                const int kw = rm % 5;
                const float val = (j == 0) ? v.x : (j == 1) ? v.y : (j == 2) ? v.z : v.w;
                wt[xi][o][c * 30 + kh * 6 + kw + xi] = bf16r(val);
            }
        }
    }
    if (tid < XT * OC) {
        const int xi = tid >> 5, o = tid & 31;
        bl[xi][o] = bias[(size_t)(y * RX + x0 + xi) * OC + o];
    }

    // ---- stage patches: 1920 rows of 6 floats -> bf16 (L2/L3-resident x) ----
    for (int r = tid; r < BATCH * CIN * KHH; r += 256) {
        const int b  = r / (CIN * KHH);
        const int cm = r % (CIN * KHH);
        const int c  = cm / KHH;
        const int kh = cm % KHH;
        const float* src = x + (size_t)((b * CIN + c) * HW + (y + kh)) * HW + x0;
        float2 v0 = *(const float2*)(src);
        float2 v1 = *(const float2*)(src + 2);
        float2 v2 = *(const float2*)(src + 4);
        unsigned* dst = (unsigned*)&pa[b][c * 30 + kh * 6];
        dst[0] = (unsigned)bf16r(v0.x) | ((unsigned)bf16r(v0.y) << 16);
        dst[1] = (unsigned)bf16r(v1.x) | ((unsigned)bf16r(v1.y) << 16);
        dst[2] = (unsigned)bf16r(v2.x) | ((unsigned)bf16r(v2.y) << 16);
    }
    __syncthreads();

    // ---- MFMA: wave wid owns rows [wid*32, +32) x both N-tiles x both xi ----
    const int wid  = tid >> 6;
    const int lane = tid & 63;
    const int lrow = lane & 15;
    const int lgrp = lane >> 4;
    const int mbase = wid * 32;

    f32x4 acc[2][2][2];                // [mt][nt][xi]
    #pragma unroll
    for (int mt = 0; mt < 2; ++mt)
        #pragma unroll
        for (int nt = 0; nt < 2; ++nt)
            #pragma unroll
            for (int xi = 0; xi < 2; ++xi)
                acc[mt][nt][xi] = (f32x4){0.f, 0.f, 0.f, 0.f};

    #pragma unroll
    for (int ks = 0; ks < 3; ++ks) {
        const int koff = ks * 32 + lgrp * 8;
        const short8 af0 = *(const short8*)&pa[mbase + lrow][koff];
        const short8 af1 = *(const short8*)&pa[mbase + 16 + lrow][koff];
        const short8 b00 = *(const short8*)&wt[0][lrow][koff];
        const short8 b10 = *(const short8*)&wt[1][lrow][koff];
        const short8 b01 = *(const short8*)&wt[0][16 + lrow][koff];
        const short8 b11 = *(const short8*)&wt[1][16 + lrow][koff];
        acc[0][0][0] = __builtin_amdgcn_mfma_f32_16x16x32_bf16(af0, b00, acc[0][0][0], 0, 0, 0);
        acc[0][0][1] = __builtin_amdgcn_mfma_f32_16x16x32_bf16(af0, b10, acc[0][0][1], 0, 0, 0);
        acc[0][1][0] = __builtin_amdgcn_mfma_f32_16x16x32_bf16(af0, b01, acc[0][1][0], 0, 0, 0);
        acc[0][1][1] = __builtin_amdgcn_mfma_f32_16x16x32_bf16(af0, b11, acc[0][1][1], 0, 0, 0);
        acc[1][0][0] = __builtin_amdgcn_mfma_f32_16x16x32_bf16(af1, b00, acc[1][0][0], 0, 0, 0);
        acc[1][0][1] = __builtin_amdgcn_mfma_f32_16x16x32_bf16(af1, b10, acc[1][0][1], 0, 0, 0);
        acc[1][1][0] = __builtin_amdgcn_mfma_f32_16x16x32_bf16(af1, b01, acc[1][1][0], 0, 0, 0);
        acc[1][1][1] = __builtin_amdgcn_mfma_f32_16x16x32_bf16(af1, b11, acc[1][1][1], 0, 0, 0);
    }

    if (COAL) {
        // tmp[pos_pair][c = b*32+o][xi]: wave store = 4 x 128B full-line chunks
        float* tbase = tmp + (size_t)(y * 30 + xp) * (BATCH * OC * XT);
        #pragma unroll
        for (int mt = 0; mt < 2; ++mt) {
            #pragma unroll
            for (int nt = 0; nt < 2; ++nt) {
                const int o = nt * 16 + lrow;
                const float bv0 = bl[0][o];
                const float bv1 = bl[1][o];
                #pragma unroll
                for (int r = 0; r < 4; ++r) {
                    const int b = mbase + mt * 16 + lgrp * 4 + r;
                    float2 v;
                    v.x = acc[mt][nt][0][r] + bv0;
                    v.y = acc[mt][nt][1][r] + bv1;
                    *(float2*)(tbase + (size_t)(b * OC + o) * 2) = v;
                }
            }
        }
    } else {
        const int pos = y * RX + x0;
        #pragma unroll
        for (int mt = 0; mt < 2; ++mt) {
            #pragma unroll
            for (int nt = 0; nt < 2; ++nt) {
                const int o = nt * 16 + lrow;
                const float bv0 = bl[0][o];
                const float bv1 = bl[1][o];
                const int brow = mbase + mt * 16 + lgrp * 4;
                #pragma unroll
                for (int r = 0; r < 4; ++r) {
                    float2 v;
                    v.x = acc[mt][nt][0][r] + bv0;
                    v.y = acc[mt][nt][1][r] + bv1;
                    *(float2*)(outp + (size_t)((brow + r) * OC + o) * (RY * RX) + pos) = v;
                }
            }
        }
    }
}

// Phase 2: tmp[y][xp][c][xi] -> out[c][y*60 + xp*2+xi], c = b*32+o in [0,4096)
__global__ __launch_bounds__(256) void lc2d_k2(
    const float* __restrict__ tmp, float* __restrict__ out)
{
    __shared__ float tile[64][65];
    const int y  = blockIdx.y;
    const int cb = blockIdx.x * 64;

    for (int i = threadIdx.x; i < 30 * 64; i += 256) {
        const int xp = i >> 6;
        const int cx = i & 63;
        const float2 v = *(const float2*)(tmp + ((size_t)(y * 30 + xp) * 4096 + cb + cx) * 2);
        tile[cx][xp * 2]     = v.x;
        tile[cx][xp * 2 + 1] = v.y;
    }
    __syncthreads();

    for (int i = threadIdx.x; i < 64 * 60; i += 256) {
        const int cl = i / 60;
        const int xx = i % 60;
        out[(size_t)(cb + cl) * (RY * RX) + y * RX + xx] = tile[cl][xx];
    }
}

extern "C" void kernel_launch(void* const* d_in, const int* in_sizes, int n_in,
                              void* d_out, int out_size, void* d_ws, size_t ws_size,
                              hipStream_t stream) {
    const float* x    = (const float*)d_in[0];
    const float* w    = (const float*)d_in[1];
    const float* bias = (const float*)d_in[2];
    float* out        = (float*)d_out;
    float* tmp        = (float*)d_ws;

    const size_t tmp_bytes = (size_t)RY * RX * BATCH * OC * sizeof(float); // 59 MB

    if (ws_size >= tmp_bytes) {
        lc2d_k1<true><<<1800, 256, 0, stream>>>(x, w, bias, out, tmp);
        lc2d_k2<<<dim3(64, 60), 256, 0, stream>>>(tmp, out);
    } else {
        lc2d_k1<false><<<1800, 256, 0, stream>>>(x, w, bias, out, tmp);
    }
}